// Round 1
// baseline (127.822 us; speedup 1.0000x reference)
//
#include <hip/hip_runtime.h>

// Problem constants
#define BSZ 16
#define NN  128
#define HH  256
#define LLG 9
#define FFE 48   // edge feature dim (padded to 64 for MFMA K)

typedef float        f32x4 __attribute__((ext_vector_type(4)));
typedef _Float16     f16x8 __attribute__((ext_vector_type(8)));
typedef _Float16     f16x2 __attribute__((ext_vector_type(2)));
typedef unsigned int u32x4 __attribute__((ext_vector_type(4)));

static __device__ __forceinline__ unsigned short f2h_bits(float x) {
    _Float16 h = (_Float16)x;   // RNE
    return __builtin_bit_cast(unsigned short, h);
}

static __device__ __forceinline__ float fast_silu(float x) {
    // silu(x) = x * sigmoid(x); v_exp_f32 + v_rcp_f32, both ~1ulp
    float e = __builtin_amdgcn_exp2f(x * -1.44269504088896341f);
    return x * __builtin_amdgcn_rcpf(1.0f + e);
}

// ---------------------------------------------------------------------------
// Kernel 1: weight transpose + f32->f16 convert.
//   WeT[h][f]  (256 x 64, f>=48 zero-padded)  from W1 rows 521..568
//   W2T[ho][k] (256 x 256)                    from W2[k][ho]
// ---------------------------------------------------------------------------
__global__ __launch_bounds__(256) void pre_w(
    const float* __restrict__ W1, const float* __restrict__ W2,
    unsigned short* __restrict__ W2T, unsigned short* __restrict__ WeT)
{
    int tid = blockIdx.x * 256 + threadIdx.x;   // grid 256 -> 65536 threads
    {
        int ho = tid >> 8, k = tid & 255;
        W2T[(ho << 8) + k] = f2h_bits(W2[(k << 8) + ho]);  // coalesced write
    }
    if (tid < 256 * 64) {
        int h = tid >> 6, f = tid & 63;
        WeT[(h << 6) + f] = (f < FFE) ? f2h_bits(W1[(521 + f) * HH + h])
                                      : (unsigned short)0;
    }
}

// ---------------------------------------------------------------------------
// Kernel 2: pj[b,r,h] = node[b,r,:] @ Wj ;  base[b,r,h] = node@Wi + graph@Wg + b1
// 256 blocks, each handles 8 node rows; W1 columns streamed once per block.
// ---------------------------------------------------------------------------
__global__ __launch_bounds__(256) void pre_pjbase(
    const float* __restrict__ node, const float* __restrict__ graph,
    const float* __restrict__ W1, const float* __restrict__ b1,
    float* __restrict__ pj, float* __restrict__ base)
{
    __shared__ float nrow[8][HH];
    __shared__ float gsh[LLG];
    const int blk = blockIdx.x;
    const int b = blk >> 4;             // 16 row-groups of 8 per batch
    const int r0 = (blk & 15) << 3;
    const int h = threadIdx.x;

    for (int t = h; t < 8 * HH; t += 256) {
        int r = t >> 8, k = t & 255;
        nrow[r][k] = node[(((size_t)b * NN) + r0 + r) * HH + k];
    }
    if (h < LLG) gsh[h] = graph[b * LLG + h];
    __syncthreads();

    float accj[8] = {0,0,0,0,0,0,0,0};
    float acci[8] = {0,0,0,0,0,0,0,0};
    for (int k = 0; k < HH; ++k) {
        float wj = W1[k * HH + h];
        float wi = W1[(k + HH) * HH + h];
        #pragma unroll
        for (int r = 0; r < 8; ++r) {
            float nv = nrow[r][k];
            accj[r] = fmaf(nv, wj, accj[r]);
            acci[r] = fmaf(nv, wi, acci[r]);
        }
    }
    float accg = b1[h];
    #pragma unroll
    for (int l = 0; l < LLG; ++l)
        accg = fmaf(gsh[l], W1[(2 * HH + l) * HH + h], accg);

    #pragma unroll
    for (int r = 0; r < 8; ++r) {
        size_t off = (((size_t)b * NN) + r0 + r) * HH + h;
        pj[off]   = accj[r];
        base[off] = acci[r] + accg;
    }
}

// ---------------------------------------------------------------------------
// Kernel 3: fused main. One block per (b,i); 4 waves.
//   GEMM1 (swapped): D1[h,j] = sum_f WeT[h][f] * edge[j][f]      (K=64 padded)
//   z1 = D1 + base[i][h] + pj[j][h];  h1 = silu(z1) -> LDS f16 (XOR-swizzled)
//   GEMM2: D2[j,ho] = sum_k h1[j][k] * W2T[ho][k]                (K=256)
//   out[b,i,ho] = mean_j silu(D2 + b2[ho])
// ---------------------------------------------------------------------------
__global__ __launch_bounds__(256, 2) void fused_msg(
    const float* __restrict__ edge, const float* __restrict__ pj,
    const float* __restrict__ base, const unsigned short* __restrict__ W2T,
    const unsigned short* __restrict__ WeT, const float* __restrict__ b2,
    float* __restrict__ out)
{
    __shared__ unsigned char h1s[NN * HH * 2];   // 64 KB: h1[j][h] f16, swizzled
    const int tid  = threadIdx.x;
    const int w    = tid >> 6;         // wave 0..3 (owns h-range w*64..)
    const int lane = tid & 63;
    const int q    = lane >> 4;        // quad 0..3
    const int c    = lane & 15;
    const int bi   = blockIdx.x;       // b*128 + i
    const int b    = bi >> 7;

    // ------------------ GEMM1: D1[h, j] ------------------
    f32x4 acc1[4][8];
    #pragma unroll
    for (int mt = 0; mt < 4; ++mt)
        #pragma unroll
        for (int nt = 0; nt < 8; ++nt) acc1[mt][nt] = f32x4{0.f, 0.f, 0.f, 0.f};

    const float* eb = edge + (size_t)bi * (NN * FFE);
    #pragma unroll
    for (int kk = 0; kk < 2; ++kk) {
        const int koff = (kk << 5) + (q << 3);   // f offset 0..56
        f16x8 af[4];
        #pragma unroll
        for (int mt = 0; mt < 4; ++mt) {
            const int row = (w << 6) + (mt << 4) + c;       // h
            af[mt] = *reinterpret_cast<const f16x8*>(WeT + (row << 6) + koff);
        }
        #pragma unroll
        for (int nt = 0; nt < 8; ++nt) {
            f16x8 bf;
            if (koff < FFE) {
                const float* p = eb + ((nt << 4) + c) * FFE + koff;
                f32x4 x0 = *reinterpret_cast<const f32x4*>(p);
                f32x4 x1 = *reinterpret_cast<const f32x4*>(p + 4);
                bf[0] = (_Float16)x0[0]; bf[1] = (_Float16)x0[1];
                bf[2] = (_Float16)x0[2]; bf[3] = (_Float16)x0[3];
                bf[4] = (_Float16)x1[0]; bf[5] = (_Float16)x1[1];
                bf[6] = (_Float16)x1[2]; bf[7] = (_Float16)x1[3];
            } else {
                u32x4 z = {0u, 0u, 0u, 0u};
                bf = __builtin_bit_cast(f16x8, z);
            }
            #pragma unroll
            for (int mt = 0; mt < 4; ++mt)
                acc1[mt][nt] = __builtin_amdgcn_mfma_f32_16x16x32_f16(
                    af[mt], bf, acc1[mt][nt], 0, 0, 0);
        }
    }

    // epilogue 1: z1 -> silu -> f16 -> LDS (swizzle: byte ^= (j&7)<<4)
    #pragma unroll
    for (int mt = 0; mt < 4; ++mt) {
        const int h0 = (w << 6) + (mt << 4) + (q << 2);
        const f32x4 bb = *reinterpret_cast<const f32x4*>(base + ((size_t)bi << 8) + h0);
        #pragma unroll
        for (int nt = 0; nt < 8; ++nt) {
            const int j = (nt << 4) + c;
            const f32x4 pjv = *reinterpret_cast<const f32x4*>(
                pj + (((size_t)b << 7) + j) * HH + h0);
            float s0 = fast_silu(acc1[mt][nt][0] + bb[0] + pjv[0]);
            float s1 = fast_silu(acc1[mt][nt][1] + bb[1] + pjv[1]);
            float s2 = fast_silu(acc1[mt][nt][2] + bb[2] + pjv[2]);
            float s3 = fast_silu(acc1[mt][nt][3] + bb[3] + pjv[3]);
            unsigned int lo = __builtin_bit_cast(unsigned int,
                                __builtin_amdgcn_cvt_pkrtz(s0, s1));
            unsigned int hi = __builtin_bit_cast(unsigned int,
                                __builtin_amdgcn_cvt_pkrtz(s2, s3));
            const unsigned int off =
                (unsigned)(j << 9) + (((unsigned)(h0 << 1)) ^ ((unsigned)(j & 7) << 4));
            *reinterpret_cast<uint2*>(&h1s[off]) = make_uint2(lo, hi);
        }
    }
    __syncthreads();

    // ------------------ GEMM2: D2[j, ho] ------------------
    f32x4 acc2[8][4];
    #pragma unroll
    for (int mt = 0; mt < 8; ++mt)
        #pragma unroll
        for (int nt = 0; nt < 4; ++nt) acc2[mt][nt] = f32x4{0.f, 0.f, 0.f, 0.f};

    #pragma unroll 2
    for (int kk = 0; kk < 8; ++kk) {
        f16x8 a2[8];
        #pragma unroll
        for (int mt = 0; mt < 8; ++mt) {
            const int j = (mt << 4) + c;
            const unsigned int off = (unsigned)(j << 9) +
                (((unsigned)((kk << 6) + (q << 4))) ^ ((unsigned)(j & 7) << 4));
            a2[mt] = *reinterpret_cast<const f16x8*>(&h1s[off]);
        }
        #pragma unroll
        for (int nt = 0; nt < 4; ++nt) {
            const int ho = (w << 6) + (nt << 4) + c;
            const f16x8 bw = *reinterpret_cast<const f16x8*>(
                W2T + (ho << 8) + (kk << 5) + (q << 3));
            #pragma unroll
            for (int mt = 0; mt < 8; ++mt)
                acc2[mt][nt] = __builtin_amdgcn_mfma_f32_16x16x32_f16(
                    a2[mt], bw, acc2[mt][nt], 0, 0, 0);
        }
    }

    // epilogue 2: silu + reduce over j (rows), butterfly across quads
    float s[4] = {0.f, 0.f, 0.f, 0.f};
    #pragma unroll
    for (int nt = 0; nt < 4; ++nt) {
        const float b2v = b2[(w << 6) + (nt << 4) + c];
        #pragma unroll
        for (int mt = 0; mt < 8; ++mt) {
            #pragma unroll
            for (int r = 0; r < 4; ++r)
                s[nt] += fast_silu(acc2[mt][nt][r] + b2v);
        }
    }
    #pragma unroll
    for (int nt = 0; nt < 4; ++nt) {
        s[nt] += __shfl_xor(s[nt], 16);
        s[nt] += __shfl_xor(s[nt], 32);
    }
    float v = (q == 0) ? s[0] : (q == 1) ? s[1] : (q == 2) ? s[2] : s[3];
    out[((size_t)bi << 8) + (w << 6) + lane] = v * 0.0078125f;  // /128
}

// ---------------------------------------------------------------------------
extern "C" void kernel_launch(void* const* d_in, const int* in_sizes, int n_in,
                              void* d_out, int out_size, void* d_ws, size_t ws_size,
                              hipStream_t stream)
{
    const float* node  = (const float*)d_in[0];
    const float* edge  = (const float*)d_in[1];
    const float* graph = (const float*)d_in[2];
    const float* W1    = (const float*)d_in[3];
    const float* b1    = (const float*)d_in[4];
    const float* W2    = (const float*)d_in[5];
    const float* b2    = (const float*)d_in[6];
    float* out = (float*)d_out;

    char* ws = (char*)d_ws;
    unsigned short* W2T = (unsigned short*)ws;              // 131072 B
    unsigned short* WeT = (unsigned short*)(ws + 131072);   //  32768 B
    float* pj   = (float*)(ws + 163840);                    // 2 MB
    float* base = (float*)(ws + 163840 + 2097152);          // 2 MB

    pre_w     <<<256, 256, 0, stream>>>(W1, W2, W2T, WeT);
    pre_pjbase<<<256, 256, 0, stream>>>(node, graph, W1, b1, pj, base);
    fused_msg <<<BSZ * NN, 256, 0, stream>>>(edge, pj, base, W2T, WeT, b2, out);
}